// Round 2
// baseline (368.498 us; speedup 1.0000x reference)
//
#include <hip/hip_runtime.h>
#include <stdint.h>

typedef unsigned short u16;
typedef __attribute__((ext_vector_type(8))) short bf16x8;
typedef __attribute__((ext_vector_type(4))) float f32x4;

#define C_IN    64
#define K_OUT   128
#define HW      112
#define HW2     (HW * HW)   // 12544
#define CP      72          // padded channel pitch (u16): 144 B rows -> 16B-aligned, bank stride 4
#define ROWP    113         // plane pitch in rows; plane p's w'=113 pad == plane p+1's w'=0 pad
#define THREADS 256

// round-to-nearest-even fp32 -> bf16 (finite inputs)
__device__ __forceinline__ u16 f2bf(float f) {
  union { float f; uint32_t u; } x; x.f = f;
  return (u16)((x.u + 0x7FFFu + ((x.u >> 16) & 1u)) >> 16);
}
__device__ __forceinline__ uint32_t pack2(float lo, float hi) {
  return (uint32_t)f2bf(lo) | ((uint32_t)f2bf(hi) << 16);
}

// OIHW fp32 weights -> bf16 wt[(rs*K_OUT + kout)*C_IN + c]  (c contiguous)
__global__ void prep_weights(const float* __restrict__ w, u16* __restrict__ wt) {
  int idx = blockIdx.x * 256 + threadIdx.x;
  if (idx >= K_OUT * C_IN * 9) return;
  int c    = idx & (C_IN - 1);
  int kout = (idx >> 6) & (K_OUT - 1);
  int rs   = idx >> 13;
  wt[idx] = f2bf(w[(kout * C_IN + c) * 9 + rs]);
}

// Block: (n, h-pair). 4 waves = {h_sub 0,1} x {kout half 0,1}; each wave: 64 kout x 112 w.
// X tile: 4 input rows [h0-1 .. h0+2] as bf16 [plane][w'][c], planes share zero pad rows.
__global__ __launch_bounds__(THREADS, 2) void conv3x3(
    const float* __restrict__ x, const u16* __restrict__ wt,
    const float* __restrict__ bias, float* __restrict__ out) {
  // flat [4*ROWP + 1][CP]: plane p rows at [p*ROWP + w'], w' in [0,113]
  __shared__ u16 Xs[4 * ROWP + 1][CP];  // 453*72*2 = 65232 B

  const int tid = threadIdx.x;
  const int bid = blockIdx.x;
  const int n  = bid / (HW / 2);
  const int h0 = (bid % (HW / 2)) * 2;

  // ---- zero shared pad rows (w'=0/113 of each plane): 5 rows x 32 dwords ----
  if (tid < 160) {
    int q  = tid >> 5;          // 0..4
    int cp = tid & 31;
    ((uint32_t*)&Xs[q * ROWP][0])[cp] = 0u;
  }

  // ---- stage 4 input rows as bf16, conflict-free LDS writes (lane-major = channel) ----
  const float* xn = x + (size_t)n * C_IN * HW2;
#pragma unroll
  for (int i = 0; i < 14; ++i) {            // 4 p x 28 w4 x 32 cp = 3584 tasks
    int t  = tid + i * THREADS;
    int cp = t & 31;                        // channel pair: c = 2*cp, 2*cp+1
    int rest = t >> 5;                      // [0,112)
    int w4 = rest % 28;                     // float4 index along w
    int p  = rest / 28;                     // plane 0..3
    int row = h0 - 1 + p;
    float4 va = {0.f, 0.f, 0.f, 0.f}, vb = va;
    if ((unsigned)row < (unsigned)HW) {
      const float* src = xn + (size_t)(2 * cp) * HW2 + row * HW + w4 * 4;
      va = *(const float4*)src;
      vb = *(const float4*)(src + HW2);
    }
    // dword index = (p*ROWP + 1 + 4*w4 + k)*36 + cp ; consecutive lanes -> consecutive banks
    uint32_t* dst = (uint32_t*)&Xs[p * ROWP + 1 + 4 * w4][0] + cp;
    dst[0]   = pack2(va.x, vb.x);
    dst[36]  = pack2(va.y, vb.y);
    dst[72]  = pack2(va.z, vb.z);
    dst[108] = pack2(va.w, vb.w);
  }
  __syncthreads();  // the ONLY barrier

  const int lane  = tid & 63;
  const int wave  = tid >> 6;
  const int quad  = lane >> 4;
  const int l15   = lane & 15;
  const int h_sub = wave >> 1;
  const int kb    = (wave & 1) * 64;   // wave's kout base (64 kouts, 4 m-tiles)

  f32x4 acc[4][7];
#pragma unroll
  for (int i = 0; i < 4; ++i)
#pragma unroll
    for (int j = 0; j < 7; ++j) acc[i][j] = (f32x4){0.f, 0.f, 0.f, 0.f};

#pragma unroll
  for (int rs = 0; rs < 9; ++rs) {
    const int r = rs / 3, s = rs % 3;
    const u16* wbase = wt + (size_t)(rs * K_OUT + kb + l15) * C_IN;
    const int xrow0 = (h_sub + r) * ROWP + s;
#pragma unroll
    for (int ch = 0; ch < 2; ++ch) {
      const int c0 = ch * 32 + quad * 8;
      // A[m=l15][k=quad*8+j] for 4 m-tiles — straight from L2-hot wt
      bf16x8 a0 = *(const bf16x8*)(wbase + c0);
      bf16x8 a1 = *(const bf16x8*)(wbase + 16 * C_IN + c0);
      bf16x8 a2 = *(const bf16x8*)(wbase + 32 * C_IN + c0);
      bf16x8 a3 = *(const bf16x8*)(wbase + 48 * C_IN + c0);
#pragma unroll
      for (int w7 = 0; w7 < 7; ++w7) {
        // B[k=quad*8+j][nn=l15] -> Xs row = plane + (w + s), w = w7*16+l15
        bf16x8 b = *(const bf16x8*)&Xs[xrow0 + w7 * 16 + l15][c0];
        acc[0][w7] = __builtin_amdgcn_mfma_f32_16x16x32_bf16(a0, b, acc[0][w7], 0, 0, 0);
        acc[1][w7] = __builtin_amdgcn_mfma_f32_16x16x32_bf16(a1, b, acc[1][w7], 0, 0, 0);
        acc[2][w7] = __builtin_amdgcn_mfma_f32_16x16x32_bf16(a2, b, acc[2][w7], 0, 0, 0);
        acc[3][w7] = __builtin_amdgcn_mfma_f32_16x16x32_bf16(a3, b, acc[3][w7], 0, 0, 0);
      }
    }
  }

  // ---- epilogue: D row = quad*4 + rg (kout within m-tile), col = l15 (w) ----
  const int h = h0 + h_sub;
  float* obase = out + ((size_t)n * K_OUT + kb) * HW2 + h * HW + l15;
#pragma unroll
  for (int mt = 0; mt < 4; ++mt) {
#pragma unroll
    for (int rg = 0; rg < 4; ++rg) {
      const int kl = mt * 16 + quad * 4 + rg;
      const float bv = bias[kb + kl];
      float* orow = obase + (size_t)kl * HW2;
#pragma unroll
      for (int w7 = 0; w7 < 7; ++w7) {
        orow[w7 * 16] = acc[mt][w7][rg] + bv;
      }
    }
  }
}

extern "C" void kernel_launch(void* const* d_in, const int* in_sizes, int n_in,
                              void* d_out, int out_size, void* d_ws, size_t ws_size,
                              hipStream_t stream) {
  const float* x  = (const float*)d_in[0];
  const float* w  = (const float*)d_in[1];
  const float* bi = (const float*)d_in[2];
  float* out = (float*)d_out;
  u16* wt = (u16*)d_ws;  // 9*128*64*2 = 147456 B of scratch

  prep_weights<<<(K_OUT * C_IN * 9 + 255) / 256, 256, 0, stream>>>(w, wt);
  conv3x3<<<32 * (HW / 2), THREADS, 0, stream>>>(x, wt, bi, out);
}